// Round 7
// baseline (201.024 us; speedup 1.0000x reference)
//
#include <hip/hip_runtime.h>
#include <math.h>

#define IMG_W 512
#define IMG_H 512
#define NPLANES 48      // 16 * 3
#define RROWS 64        // output rows per wave (512 = 64*8 exact)
#define NCHUNK 8        // 512 / RROWS
#define NSTRIP 8        // 512 / 64 cols
#define WPB 4           // waves per block (256 threads)
#define NGROUP (NCHUNK / WPB)                  // 2 chunk-groups per strip
#define NBLOCKS (NPLANES * NSTRIP * NGROUP)    // 768 blocks = 3 blocks/CU exact
#define NPAIRS (RROWS / 2 + 5)                 // 37 input row-pairs per wave
#define SSIM_C1 1e-4f
#define SSIM_C2 9e-4f

typedef float f32x2 __attribute__((ext_vector_type(2)));
typedef float f32x4 __attribute__((ext_vector_type(4)));

struct GW { float g[11]; };

__device__ __forceinline__ f32x2 splat2(float v) { return (f32x2){v, v}; }
__device__ __forceinline__ f32x2 fma2(f32x2 a, f32x2 b, f32x2 c) {
  return __builtin_elementwise_fma(a, b, c);   // -> v_pk_fma_f32 on gfx950
}

// Packed Newton division (verified round 6). Per-element op sequence
// identical to the scalar fdiv_fast -> bit-identical per element.
__device__ __forceinline__ f32x2 fdiv_fast2(f32x2 n, f32x2 d) {
  f32x2 r = { __builtin_amdgcn_rcpf(d.x), __builtin_amdgcn_rcpf(d.y) };
  r = r * fma2(-d, r, splat2(2.0f));      // 1 Newton step on reciprocal
  f32x2 q = n * r;
  q = fma2(fma2(-d, q, n), r, q);         // residual correction
  return q;
}

// ORDERING NOTE (root cause of the round-3/4 failures, fix verified round 5):
// the no-barrier LDS pipeline needs cross-lane write->read ordering. Per
// thread, [t] and [t+k] (k>=1) are provably-distinct LDS addresses, so the
// compiler may legally reorder vector ds_reads around ds_writes — correct
// per-thread, wrong cross-lane. HW executes a wave's DS ops in issue order,
// so COMPILER fences suffice. The decoupled pipeline below needs TWO per
// iteration: (1) start-fence: prev iter's reads of buffer X precede this
// iter's writes of X (buffers alternate with period 2, stage is 1 ahead of
// consume, so the overwritten buffer was read LAST iteration); (2) mid-fence:
// this iter's writes precede this iter's reads. Register-only ops move
// freely across asm memory fences, so VALU scheduling is unaffected.
#define LDS_ORDER_FENCE() asm volatile("" ::: "memory")

// Decoupled row-pair pipeline (round 7): at iteration ii the wave
//   (a) stages pair ii+1 to LDS (its loads were issued at iter ii-2),
//   (b) issues global loads for pair ii+3 into a 3-deep rotating reg set,
//   (c) consumes pair ii from LDS — written one FULL iteration ago, so the
//       ds_write->ds_read latency (~120cy) is off the critical path, and
//   VMEM issue->use distance is ~2 iterations (~1400cy > ~900cy HBM miss).
// Round 6 staged and consumed the same pair in one iteration: both the LDS
// write->read wait and a ~1-iteration VMEM window sat in the critical path
// every iteration (VALUBusy 63%, ~2 waves/SIMD can't hide the rest).
// Rotation indices are compile-time after the 6-way unroll: ii%3 == ph%3,
// ii&1 == ph&1 (6 is a multiple of both periods) -> no scratch (rule: keep
// register-array indices static).
// All arithmetic (h-conv packing, ring, vertical conv, SSIM map, packed
// division) is byte-identical to round 6.
__global__ __launch_bounds__(256, 2) void ssim_main(
    const float* __restrict__ A, const float* __restrict__ B,
    const float* __restrict__ F, double* __restrict__ partials, GW gw)
{
  __shared__ f32x4 sAB[WPB][2][80];   // (A0,A1,B0,B1) per column
  __shared__ f32x2 sFF[WPB][2][80];   // (F0,F1) per column
  __shared__ double sred[WPB];
  const int b = blockIdx.x;
  const int plane = b / (NSTRIP * NGROUP);
  const int rem   = b % (NSTRIP * NGROUP);
  const int strip = rem / NGROUP;
  const int grp   = rem % NGROUP;
  const int wid = threadIdx.x >> 6;      // wave id 0..3
  const int t   = threadIdx.x & 63;      // lane id
  const int chunk = grp * WPB + wid;     // 0..7
  const int x0 = strip * 64;
  const int y0 = chunk * RROWS;
  const size_t pbase = (size_t)plane * (IMG_W * IMG_H);
  const float* Ap = A + pbase;
  const float* Bp = B + pbase;
  const float* Fp = F + pbase;

  // this wave's private LDS slices
  f32x4 (&mAB)[2][80] = sAB[wid];
  f32x2 (&mFF)[2][80] = sFF[wid];

  const int c  = x0 - 5 + t;                 // primary load column
  const bool cok = (c >= 0) && (c < IMG_W);
  const int c2 = c + 64;                     // halo column (lanes 0..9)
  const bool c2ok = (t < 10) && (c2 < IMG_W);

  // ring[stream][slot]: horizontally-convolved ROW PAIRS, slot = pair mod 6
  f32x2 ring[7][6];
  #pragma unroll
  for (int s = 0; s < 7; ++s)
    #pragma unroll
    for (int k = 0; k < 6; ++k) ring[s][k] = splat2(0.f);

  float acc = 0.f;

  // 3-deep rotating prefetch sets: pair p lives in set p%3.
  // Set p%3 is staged to LDS at iter p-1 and reloaded (pair p+3) at iter p
  // -> one-iteration gap, no write-after-read pressure.
  float rA0[3],rA1[3],rB0[3],rB1[3],rF0[3],rF1[3];
  float xA0[3],xA1[3],xB0[3],xB1[3],xF0[3],xF1[3];
  auto load_pair = [&](int ii, int set) {
    const int yin0 = y0 - 5 + 2*ii;
    const int yin1 = yin0 + 1;
    const bool r0 = (yin0 >= 0) && (yin0 < IMG_H);
    const bool r1 = (yin1 >= 0) && (yin1 < IMG_H);
    const size_t o0 = (size_t)yin0 * IMG_W;
    const size_t o1 = (size_t)yin1 * IMG_W;
    rA0[set] = (r0 && cok) ? Ap[o0 + c] : 0.f;
    rB0[set] = (r0 && cok) ? Bp[o0 + c] : 0.f;
    rF0[set] = (r0 && cok) ? Fp[o0 + c] : 0.f;
    rA1[set] = (r1 && cok) ? Ap[o1 + c] : 0.f;
    rB1[set] = (r1 && cok) ? Bp[o1 + c] : 0.f;
    rF1[set] = (r1 && cok) ? Fp[o1 + c] : 0.f;
    xA0[set] = (r0 && c2ok) ? Ap[o0 + c2] : 0.f;
    xB0[set] = (r0 && c2ok) ? Bp[o0 + c2] : 0.f;
    xF0[set] = (r0 && c2ok) ? Fp[o0 + c2] : 0.f;
    xA1[set] = (r1 && c2ok) ? Ap[o1 + c2] : 0.f;
    xB1[set] = (r1 && c2ok) ? Bp[o1 + c2] : 0.f;
    xF1[set] = (r1 && c2ok) ? Fp[o1 + c2] : 0.f;
  };

  // prologue: 3 pairs in flight, pair 0 staged to LDS buffer 0
  load_pair(0, 0);
  load_pair(1, 1);
  load_pair(2, 2);
  mAB[0][t] = (f32x4){rA0[0], rA1[0], rB0[0], rB1[0]};
  mFF[0][t] = (f32x2){rF0[0], rF1[0]};
  if (t < 10) {
    mAB[0][t+64] = (f32x4){xA0[0], xA1[0], xB0[0], xB1[0]};
    mFF[0][t+64] = (f32x2){xF0[0], xF1[0]};
  }

  for (int jj = 0; jj < 7; ++jj) {
    #pragma unroll
    for (int ph = 0; ph < 6; ++ph) {
      const int ii = jj * 6 + ph;            // pair being CONSUMED; ii%6==ph
      if (ii < NPAIRS) {                     // 37 pairs = 74 input rows
        const int rbuf = ph & 1;             // buffer holding pair ii
        const int wbuf = (ph + 1) & 1;       // buffer for pair ii+1
        const int sst  = (ph + 1) % 3;       // reg set holding pair ii+1
        const int sld  = ph % 3;             // reg set target for pair ii+3
        // prev iter's reads of wbuf precede this iter's writes (see note)
        LDS_ORDER_FENCE();
        // --- (a) stage pair ii+1 into LDS (loaded at iter ii-2) ---
        if (ii + 1 < NPAIRS) {
          mAB[wbuf][t] = (f32x4){rA0[sst], rA1[sst], rB0[sst], rB1[sst]};
          mFF[wbuf][t] = (f32x2){rF0[sst], rF1[sst]};
          if (t < 10) {
            mAB[wbuf][t+64] = (f32x4){xA0[sst], xA1[sst], xB0[sst], xB1[sst]};
            mFF[wbuf][t+64] = (f32x2){xF0[sst], xF1[sst]};
          }
        }
        // --- (b) issue loads for pair ii+3 (~2 iterations of latency cover) ---
        if (ii + 3 < NPAIRS) load_pair(ii + 3, sld);
        // this iter's writes precede this iter's reads (see note)
        LDS_ORDER_FENCE();
        // --- (c) horizontal 11-tap conv of pair ii (staged LAST iteration) ---
        f32x2 hA=splat2(0.f), hB=splat2(0.f), hF=splat2(0.f),
              hA2=splat2(0.f), hB2=splat2(0.f), hF2=splat2(0.f),
              hAF=splat2(0.f), hBF=splat2(0.f);
        #pragma unroll
        for (int k = 0; k < 11; ++k) {
          const float w = gw.g[k];
          const f32x4 ab = mAB[rbuf][t+k];    // 1x ds_read_b128
          const f32x2 f  = mFF[rbuf][t+k];    // 1x ds_read_b64
          const f32x2 a  = {ab.x, ab.y};
          const f32x2 bb = {ab.z, ab.w};
          const f32x2 wv = splat2(w);
          const f32x2 wa = wv*a, wb = wv*bb, wf = wv*f;
          hA += wa; hB += wb; hF += wf;
          hA2 = fma2(wa, a, hA2); hB2 = fma2(wb, bb, hB2); hF2 = fma2(wf, f, hF2);
          hAF = fma2(wa, f, hAF); hBF = fma2(wb, f, hBF);
        }
        // merge variance streams at ring-write (conv linearity): 7 rings
        ring[0][ph]=hA;  ring[1][ph]=hB;  ring[2][ph]=hF;
        ring[3][ph]=hA2+hF2;  ring[4][ph]=hB2+hF2;
        ring[5][ph]=hAF; ring[6][ph]=hBF;

        // --- vertical 11-tap conv + packed SSIM map ---
        if (ii >= 5) {                       // output pair j = ii-5
          f32x2 M[7];
          #pragma unroll
          for (int s = 0; s < 7; ++s) M[s] = splat2(0.f);
          #pragma unroll
          for (int k = 0; k < 11; ++k) {
            const float w = gw.g[k];
            if ((k & 1) == 0) {
              // even tap: lo/hi rows use (.x,.y) of the SAME slot -> packed
              const int p = (ph + 1 + (k >> 1)) % 6;      // compile-time
              const f32x2 wv = splat2(w);
              #pragma unroll
              for (int s = 0; s < 7; ++s) M[s] = fma2(wv, ring[s][p], M[s]);
            } else {
              // odd tap: halves of adjacent slots; scalar on register halves
              const int plo = (ph + 1 + (k >> 1)) % 6;    // compile-time
              const int phi = (plo + 1) % 6;
              #pragma unroll
              for (int s = 0; s < 7; ++s) {
                M[s].x = fmaf(w, ring[s][plo].y, M[s].x);
                M[s].y = fmaf(w, ring[s][phi].x, M[s].y);
              }
            }
          }
          const f32x2 mAv=M[0], mBv=M[1], mFv=M[2];
          const f32x2 vS1=M[3], vS2=M[4], vAF=M[5], vBF=M[6];
          const f32x2 mA2=mAv*mAv, mB2=mBv*mBv, mF2=mFv*mFv,
                      mAF=mAv*mFv, mBF=mBv*mFv;
          const f32x2 sAFv = vAF - mAF, sBFv = vBF - mBF;
          const f32x2 ts1 = vS1 - mA2 - mF2;   // sigmaA^2 + sigmaF^2
          const f32x2 ts2 = vS2 - mB2 - mF2;   // sigmaB^2 + sigmaF^2
          const f32x2 two = splat2(2.f), c1 = splat2(SSIM_C1), c2v = splat2(SSIM_C2);
          const f32x2 n1 = fma2(two, mAF, c1) * fma2(two, sAFv, c2v);
          const f32x2 d1 = (mA2 + mF2 + c1) * (ts1 + c2v);
          const f32x2 n2 = fma2(two, mBF, c1) * fma2(two, sBFv, c2v);
          const f32x2 d2 = (mB2 + mF2 + c1) * (ts2 + c2v);
          const f32x2 q1 = fdiv_fast2(n1, d1);
          const f32x2 q2 = fdiv_fast2(n2, d2);
          // accumulate in row-ascending order (bit-identical to scalar)
          acc += q1.x + q2.x;
          acc += q1.y + q2.y;
        }
      }
    }
  }

  // wave (64-lane) reduction, then one cross-wave LDS reduce per block
  float wsum = acc;
  #pragma unroll
  for (int off = 32; off > 0; off >>= 1)
    wsum += __shfl_down(wsum, off, 64);
  if (t == 0) sred[wid] = (double)wsum;
  __syncthreads();
  if (threadIdx.x == 0)
    partials[b] = sred[0] + sred[1] + sred[2] + sred[3];
}

__global__ __launch_bounds__(256) void ssim_final(
    const double* __restrict__ partials, float* __restrict__ out)
{
  __shared__ double sd[256];
  const int t = threadIdx.x;
  double s = 0.0;
  for (int i = t; i < NBLOCKS; i += 256) s += partials[i];
  sd[t] = s;
  __syncthreads();
  for (int off = 128; off > 0; off >>= 1) {
    if (t < off) sd[t] += sd[t + off];
    __syncthreads();
  }
  if (t == 0)
    out[0] = (float)(0.5 * sd[0] / (double)(16.0 * 3.0 * 512.0 * 512.0));
}

extern "C" void kernel_launch(void* const* d_in, const int* in_sizes, int n_in,
                              void* d_out, int out_size, void* d_ws, size_t ws_size,
                              hipStream_t stream) {
  const float* A = (const float*)d_in[0];
  const float* B = (const float*)d_in[1];
  const float* F = (const float*)d_in[2];
  double* partials = (double*)d_ws;   // NBLOCKS doubles = 6 KB

  GW gw;
  double g[11], s = 0.0;
  for (int i = 0; i < 11; ++i) { g[i] = exp(-((double)((i-5)*(i-5))) / 4.5); s += g[i]; }
  for (int i = 0; i < 11; ++i) gw.g[i] = (float)(g[i] / s);

  hipLaunchKernelGGL(ssim_main, dim3(NBLOCKS), dim3(WPB * 64), 0, stream,
                     A, B, F, partials, gw);
  hipLaunchKernelGGL(ssim_final, dim3(1), dim3(256), 0, stream,
                     partials, (float*)d_out);
}